// Round 8
// baseline (452.702 us; speedup 1.0000x reference)
//
#include <hip/hip_runtime.h>
#include <hip/hip_cooperative_groups.h>
#include <hip/hip_bf16.h>
#include <stdint.h>

namespace cg = cooperative_groups;

// Problem dims (fixed)
#define NB 8
#define NS 2048
#define ND 1024
#define NH 4096
#define NE 8
#define NTOK (NB*NS)   // 16384 tokens

typedef __bf16 bf16;
typedef bf16 bf16x8 __attribute__((ext_vector_type(8)));
typedef float f32x4 __attribute__((ext_vector_type(4)));

// ws layout: meta[512] ints + perm[16384] at meta+512, then:
static const size_t OFF_XB  = 128 * 1024;                          // bf16 xbp[NTOK][ND]  (PERMUTED rows)
static const size_t OFF_WTE = OFF_XB  + (size_t)NTOK * ND * 2;     // bf16 wte[NE][NH][ND]
static const size_t OFF_WTO = OFF_WTE + (size_t)NE * NH * ND * 2;  // bf16 wto[ND][NH]
static const size_t OFF_HB  = OFF_WTO + (size_t)ND * NH * 2;       // bf16 hb [NTOK][NH] (permuted rows)
static const size_t WS_NEED = OFF_HB  + (size_t)NTOK * NH * 2;

#define GLDS16(src, dst) __builtin_amdgcn_global_load_lds( \
    (__attribute__((address_space(1))) void*)(void*)(src), \
    (__attribute__((address_space(3))) void*)(dst), 16, 0, 0)

// ---------------- prep kernels (R6-validated) ----------------

__global__ void k_route(const int* __restrict__ assign, int* __restrict__ meta) {
    __shared__ int cnt[NE];
    __shared__ int offs_s[NE];
    int tid = threadIdx.x;
    if (tid < NE) cnt[tid] = 0;
    __syncthreads();
    for (int t = tid; t < NTOK; t += 1024) atomicAdd(&cnt[assign[t] & 7], 1);
    __syncthreads();
    if (tid == 0) {
        int o = 0;
        for (int e = 0; e < NE; e++) {
            meta[e] = cnt[e]; meta[16 + e] = o; offs_s[e] = o; o += cnt[e];
        }
    }
    __syncthreads();
    if (tid < NE) cnt[tid] = offs_s[tid];   // reuse as cursors
    __syncthreads();
    int* perm = meta + 512;
    for (int t = tid; t < NTOK; t += 1024) {
        int e = assign[t] & 7;
        int p = atomicAdd(&cnt[e], 1);
        perm[p] = t;
    }
}

__global__ void k_gather_cvt(const float* __restrict__ x, const int* __restrict__ meta,
                             bf16* __restrict__ xbp) {
    long i = (long)blockIdx.x * blockDim.x + threadIdx.x;   // 8 elems each
    int row = (int)(i >> 7);
    int c8  = (int)(i & 127);
    const int* perm = meta + 512;
    int tok = perm[row];
    const float4* s = (const float4*)(x + (size_t)tok * ND + c8 * 8);
    float4 v0 = s[0], v1 = s[1];
    bf16x8 o;
    o[0] = (bf16)v0.x; o[1] = (bf16)v0.y; o[2] = (bf16)v0.z; o[3] = (bf16)v0.w;
    o[4] = (bf16)v1.x; o[5] = (bf16)v1.y; o[6] = (bf16)v1.z; o[7] = (bf16)v1.w;
    *(bf16x8*)(xbp + i * 8) = o;
}

__global__ void k_transpose(const float* __restrict__ in, bf16* __restrict__ out,
                            int R, int C) {
    __shared__ float tile[32][33];
    int b  = blockIdx.z;
    int c0 = blockIdx.x * 32, r0 = blockIdx.y * 32;
    const float* inb = in + (size_t)b * R * C;
    bf16* outb = out + (size_t)b * R * C;
    int tx = threadIdx.x, ty = threadIdx.y;
#pragma unroll
    for (int i = 0; i < 4; i++) {
        int r = r0 + ty + i * 8;
        tile[ty + i * 8][tx] = inb[(size_t)r * C + c0 + tx];
    }
    __syncthreads();
#pragma unroll
    for (int i = 0; i < 4; i++) {
        int c = c0 + ty + i * 8;
        outb[(size_t)c * R + r0 + tx] = (bf16)tile[tx][ty + i * 8];
    }
}

// =====================================================================
// Fused cooperative MoE kernel: 256 blocks x 512 thr, STATIC jobs.
// Phase 1 (GEMM1): block b runs jobs {b, b+256, ...} < 1152.
//   job -> e = job&7 (block-constant expert), r2 = job>>3, j = r2%9 (m-tile),
//   bx = r2/9 (n-panel)  -- R6's verified locality decode.
// __threadfence + grid.sync()  (residency contractual via cooperative launch)
// Phase 2 (GEMM2): block b runs one m/n job via R6's XCD swizzle.
// GEMM core (R5/R6-validated): 8-phase 256x256, BK=64, 8 waves (2Mx4N),
// A 3-deep / B 2-deep LDS ring (160KB), vmcnt(8)/K-tile, XOR-swizzled
// granules (slot s of row r holds granule s^(r&7); conflict-free).
// =====================================================================

#define BAR { __builtin_amdgcn_s_barrier(); asm volatile("" ::: "memory"); }
#define VMC8 asm volatile("s_waitcnt vmcnt(8)" ::: "memory")
#define VMC0 asm volatile("s_waitcnt vmcnt(0)" ::: "memory")

#define LDA(msub) { \
  const char* Ab = sm + abuf + wr * 16384; \
  _Pragma("unroll") for (int m = 0; m < 4; m++) { \
    int row = ((msub) * 4 + m) * 16 + lr; \
    af[m][0] = *(const bf16x8*)(Ab + row * 128 + xk0); \
    af[m][1] = *(const bf16x8*)(Ab + row * 128 + xk1); \
  } }

#define LDB(nsub) { \
  const char* Bb = sm + bbuf + (wc >> 1) * 16384; \
  _Pragma("unroll") for (int n = 0; n < 2; n++) { \
    int row = (wc & 1) * 64 + ((nsub) * 2 + n) * 16 + lr; \
    bfr[(nsub)*2+n][0] = *(const bf16x8*)(Bb + row * 128 + xk0); \
    bfr[(nsub)*2+n][1] = *(const bf16x8*)(Bb + row * 128 + xk1); \
  } }

#define MFMA_Q(msub, nsub) { \
  __builtin_amdgcn_s_setprio(1); \
  _Pragma("unroll") for (int m = 0; m < 4; m++) \
  _Pragma("unroll") for (int n = 0; n < 2; n++) \
  _Pragma("unroll") for (int k = 0; k < 2; k++) \
    acc[(msub)*4+m][(nsub)*2+n] = __builtin_amdgcn_mfma_f32_16x16x32_bf16( \
        af[m][k], bfr[(nsub)*2+n][k], acc[(msub)*4+m][(nsub)*2+n], 0, 0, 0); \
  __builtin_amdgcn_s_setprio(0); }

#define DO_TILE(i, S0, S1, S2, S3, VW) { \
  const int abuf = ((i) % 3) * 32768; \
  const int bbuf = 98304 + ((i) & 1) * 32768; \
  LDA(0); LDB(0); S0; BAR; MFMA_Q(0,0); BAR; \
  LDB(1);         S1; BAR; MFMA_Q(0,1); BAR; \
  LDA(1);         S2; BAR; MFMA_Q(1,0); BAR; \
                  S3; VW; BAR; MFMA_Q(1,1); BAR; \
}

#define STAGE_A(t, h) { \
    char* d = sm + ((t) % 3) * 32768 + (h) * 16384 + wid * 1024; \
    GLDS16(srcA(t, h, 0), d); \
    GLDS16(srcA(t, h, 1), d + 8192); }
#define STAGE_B(t, h) { \
    char* d = sm + 98304 + ((t) & 1) * 32768 + (h) * 16384 + wid * 1024; \
    GLDS16(srcB(t, h, 0), d); \
    GLDS16(srcB(t, h, 1), d + 8192); }

__launch_bounds__(512, 2)
__global__ void k_moe(const bf16* __restrict__ xbp, const bf16* __restrict__ wte,
                      const bf16* __restrict__ wto, const float* __restrict__ b_e,
                      const float* __restrict__ b_out, bf16* __restrict__ hb,
                      float* __restrict__ out, const int* __restrict__ meta) {
    __shared__ __align__(16) char sm[163840];
    int tid = threadIdx.x;
    int lane = tid & 63, wid = tid >> 6;
    int wr = wid >> 2, wc = wid & 3;
    int lr = lane & 15, kg = lane >> 4;
    int xk0 = (kg ^ (lr & 7)) * 16;
    int xk1 = ((4 + kg) ^ (lr & 7)) * 16;
    int sr = tid >> 3, sl = tid & 7;
    int g = sl ^ (sr & 7);
    const int* perm = meta + 512;
    int b = blockIdx.x;

    // ---------------- phase 1: GEMM1, static jobs ----------------
    for (int q = 0; q < 5; ++q) {
        int job = q * 256 + b;
        if (job >= 1152) break;
        int e = job & 7, r2 = job >> 3;
        int jj = r2 % 9, bx = r2 / 9;
        int cnt = meta[e];
        int rs = meta[16 + e] + jj * 256;
        int rc = cnt - jj * 256; if (rc > 256) rc = 256;
        if (rc > 0) {
            int n0 = bx * 256;
            const bf16* pa[2][2];
#pragma unroll
            for (int h = 0; h < 2; h++)
#pragma unroll
                for (int rr = 0; rr < 2; rr++) {
                    int arow = h * 128 + rr * 64 + sr;
                    int p = rs + (arow < rc - 1 ? arow : rc - 1);
                    pa[h][rr] = xbp + (size_t)p * ND + g * 8;
                }
            const bf16* pb0 = wte + ((size_t)e * NH + n0 + sr) * ND + g * 8;
#define srcA(t, h, rr) (pa[h][rr] + (size_t)(t) * 64)
#define srcB(t, h, rr) (pb0 + ((h) * 128 + (rr) * 64) * (size_t)ND + (size_t)(t) * 64)
            f32x4 acc[8][4] = {};
            bf16x8 af[4][2], bfr[4][2];
            const int NT = ND / 64;   // 16
            STAGE_A(0, 0); STAGE_A(0, 1); STAGE_B(0, 0); STAGE_B(0, 1);
            STAGE_A(1, 0); STAGE_A(1, 1); STAGE_B(1, 0); STAGE_B(1, 1);
            VMC8;
            BAR;
#pragma unroll 2
            for (int i = 0; i < NT - 2; i++)
                DO_TILE(i, STAGE_A(i + 2, 0), STAGE_A(i + 2, 1),
                           STAGE_B(i + 2, 0), STAGE_B(i + 2, 1), VMC8);
            DO_TILE(NT - 2, , , , , VMC0);
            DO_TILE(NT - 1, , , , , );
#undef srcA
#undef srcB
            float bias[4];
#pragma unroll
            for (int n = 0; n < 4; n++) bias[n] = b_e[e * NH + n0 + wc * 64 + n * 16 + lr];
#pragma unroll
            for (int m = 0; m < 8; m++) {
#pragma unroll
                for (int rr = 0; rr < 4; rr++) {
                    int row = wr * 128 + m * 16 + kg * 4 + rr;
                    if (row < rc) {
                        bf16* hp = hb + (size_t)(rs + row) * NH + n0 + wc * 64;
#pragma unroll
                        for (int n = 0; n < 4; n++)
                            hp[n * 16 + lr] = (bf16)fmaxf(acc[m][n][rr] + bias[n], 0.0f);
                    }
                }
            }
        }
        __syncthreads();   // defensive: job boundary (drains stores + LDS quiesce)
    }

    __threadfence();
    cg::this_grid().sync();

    // ---------------- phase 2: GEMM2, one static job ----------------
    {
        int swz = (b & 7) * 32 + (b >> 3);      // bijective XCD swizzle, 256 blocks
        int bx = swz & 3, by = swz >> 2;
        int m0 = by * 256, n0 = bx * 256;
        const bf16* pa0 = hb  + ((size_t)m0 + sr) * NH + g * 8;
        const bf16* pb0 = wto + ((size_t)n0 + sr) * NH + g * 8;
#define srcA(t, h, rr) (pa0 + ((h) * 128 + (rr) * 64) * (size_t)NH + (size_t)(t) * 64)
#define srcB(t, h, rr) (pb0 + ((h) * 128 + (rr) * 64) * (size_t)NH + (size_t)(t) * 64)
        f32x4 acc[8][4] = {};
        bf16x8 af[4][2], bfr[4][2];
        const int NT = NH / 64;   // 64
        STAGE_A(0, 0); STAGE_A(0, 1); STAGE_B(0, 0); STAGE_B(0, 1);
        STAGE_A(1, 0); STAGE_A(1, 1); STAGE_B(1, 0); STAGE_B(1, 1);
        VMC8;
        BAR;
#pragma unroll 2
        for (int i = 0; i < NT - 2; i++)
            DO_TILE(i, STAGE_A(i + 2, 0), STAGE_A(i + 2, 1),
                       STAGE_B(i + 2, 0), STAGE_B(i + 2, 1), VMC8);
        DO_TILE(NT - 2, , , , , VMC0);
        DO_TILE(NT - 1, , , , , );
#undef srcA
#undef srcB
        float bias[4];
#pragma unroll
        for (int n = 0; n < 4; n++) bias[n] = b_out[n0 + wc * 64 + n * 16 + lr];
#pragma unroll
        for (int m = 0; m < 8; m++) {
#pragma unroll
            for (int rr = 0; rr < 4; rr++) {
                int prow = m0 + wr * 128 + m * 16 + kg * 4 + rr;
                int tok = perm[prow];
                float* op = out + (size_t)tok * ND + n0 + wc * 64;
#pragma unroll
                for (int n = 0; n < 4; n++)
                    op[n * 16 + lr] = acc[m][n][rr] + bias[n];
            }
        }
    }
}

extern "C" void kernel_launch(void* const* d_in, const int* in_sizes, int n_in,
                              void* d_out, int out_size, void* d_ws, size_t ws_size,
                              hipStream_t stream) {
    const float* x     = (const float*)d_in[0];
    const float* W_e   = (const float*)d_in[1];
    const float* b_e   = (const float*)d_in[2];
    const float* W_out = (const float*)d_in[3];
    const float* b_out = (const float*)d_in[4];
    const int*   assign = (const int*)d_in[5];
    float* out = (float*)d_out;

    if (ws_size < WS_NEED) return;

    char* ws = (char*)d_ws;
    int*  meta = (int*)ws;
    const bf16* xbp = (const bf16*)(ws + OFF_XB);
    bf16* wte = (bf16*)(ws + OFF_WTE);
    bf16* wto = (bf16*)(ws + OFF_WTO);
    bf16* hb  = (bf16*)(ws + OFF_HB);

    k_route<<<1, 1024, 0, stream>>>(assign, meta);
    k_gather_cvt<<<NTOK * ND / (256 * 8), 256, 0, stream>>>(x, meta, (bf16*)(ws + OFF_XB));
    k_transpose<<<dim3(NH / 32, ND / 32, NE), dim3(32, 8), 0, stream>>>(W_e, wte, ND, NH);
    k_transpose<<<dim3(ND / 32, NH / 32, 1), dim3(32, 8), 0, stream>>>(W_out, wto, NH, ND);

    // fused cooperative GEMM1 -> grid.sync -> GEMM2
    const bf16* wte_c = wte;
    const bf16* wto_c = wto;
    const int*  meta_c = meta;
    void* args[] = { (void*)&xbp, (void*)&wte_c, (void*)&wto_c, (void*)&b_e,
                     (void*)&b_out, (void*)&hb, (void*)&out, (void*)&meta_c };
    hipLaunchCooperativeKernel(reinterpret_cast<void*>(&k_moe),
                               dim3(256), dim3(512), args, 0, stream);
}